// Round 10
// baseline (331.037 us; speedup 1.0000x reference)
//
#include <hip/hip_runtime.h>

// GNN: N=50000 nodes, E=800000 edges, IN=128, HID=64, OUT=128, EH=32, 3 etypes, 2 ntypes.
//
// Strategy:
//   feat @ eW[e] = nf[src] @ eW[e][:IN] + nf[dst] @ eW[e][IN:]
//   => per-node projections P[n][192], per-edge work = adds + relu + reg accumulation
//      (gather over CSR-by-dst). Node MLP type-partitioned. proj via MFMA bf16 3-term split.
//
// R1: multi-block scan. R2: mlp type-partitioned. R3: CSR replicated-rank + atomic-free
//     scatter. R4/R5: conflict-free quad layouts. R6: LDS-BW floor. R7: proj MFMA.
// R8: aggregate is LATENCY-bound (Little's law ~1.5 loads/wave @900cyc = 2 TB/s).
// R9: et packed in edata low bits; unroll-4 (8 loads in flight) -> aggregate ~32us.
// R10: aggregate: contiguous row-split per slot + unroll-8 -> 16 P loads in
//      flight/wave; launches 17->13 (scan3+partition fused, prep_w fused, tcnt
//      zeroed by scan2 instead of memset).

typedef __attribute__((ext_vector_type(8))) short bf16x8_t;   // 8 bf16 in 4 VGPRs
typedef __attribute__((ext_vector_type(4))) float f32x4_t;

__device__ __forceinline__ void cvt_split(float x, unsigned short& h, unsigned short& l) {
  unsigned u = __float_as_uint(x);
  unsigned rh = u + 0x7FFFu + ((u >> 16) & 1u);
  h = (unsigned short)(rh >> 16);
  float xh = __uint_as_float((unsigned)h << 16);
  float xl = x - xh;
  unsigned v = __float_as_uint(xl);
  unsigned rl = v + 0x7FFFu + ((v >> 16) & 1u);
  l = (unsigned short)(rl >> 16);
}

// ---------------- CSR build (deg8 replicated-rank, atomic-free scatter) ----------------

__global__ __launch_bounds__(256) void rank_kernel(const int* __restrict__ dst,
                                                   int* __restrict__ deg8,
                                                   int* __restrict__ rank, int E) {
  int i = blockIdx.x * 256 + threadIdx.x;
  if (i < E) {
    int d = dst[i];
    int r = (i >> 8) & 7;
    rank[i] = atomicAdd(&deg8[d * 8 + r], 1);
  }
}

__global__ __launch_bounds__(256) void scan1_kernel(int* __restrict__ deg8,
                                                    int* __restrict__ rowstart,
                                                    int* __restrict__ bsum, int n) {
  __shared__ int tmp[256];
  int t = threadIdx.x;
  int base = blockIdx.x * 1024 + t * 4;
  int vdeg[4];
#pragma unroll
  for (int q = 0; q < 4; ++q) {
    int v = base + q;
    int d = 0;
    if (v < n) {
      int4 a = *(int4*)(deg8 + (size_t)v * 8);
      int4 b = *(int4*)(deg8 + (size_t)v * 8 + 4);
      int p1 = a.x, p2 = p1 + a.y, p3 = p2 + a.z, p4 = p3 + a.w;
      int p5 = p4 + b.x, p6 = p5 + b.y, p7 = p6 + b.z;
      d = p7 + b.w;
      *(int4*)(deg8 + (size_t)v * 8) = make_int4(0, p1, p2, p3);
      *(int4*)(deg8 + (size_t)v * 8 + 4) = make_int4(p4, p5, p6, p7);
    }
    vdeg[q] = d;
  }
  int s = vdeg[0] + vdeg[1] + vdeg[2] + vdeg[3];
  tmp[t] = s;
  __syncthreads();
  for (int off = 1; off < 256; off <<= 1) {
    int u = (t >= off) ? tmp[t - off] : 0;
    __syncthreads();
    tmp[t] += u;
    __syncthreads();
  }
  int excl = tmp[t] - s;
  if (base < n)     rowstart[base]     = excl;
  if (base + 1 < n) rowstart[base + 1] = excl + vdeg[0];
  if (base + 2 < n) rowstart[base + 2] = excl + vdeg[0] + vdeg[1];
  if (base + 3 < n) rowstart[base + 3] = excl + vdeg[0] + vdeg[1] + vdeg[2];
  if (t == 255) bsum[blockIdx.x] = tmp[255];
}

// also zeroes tcnt (runs before the fused scan3+partition)
__global__ __launch_bounds__(64) void scan2_kernel(const int* __restrict__ bsum,
                                                   int* __restrict__ boff, int nb,
                                                   int* __restrict__ rowstart, int n,
                                                   int* __restrict__ tcnt) {
  int lane = threadIdx.x;
  int v = (lane < nb) ? bsum[lane] : 0;
  int incl = v;
  for (int off = 1; off < 64; off <<= 1) {
    int u = __shfl_up(incl, off, 64);
    if (lane >= off) incl += u;
  }
  if (lane < nb) boff[lane] = incl - v;
  if (lane == 63) rowstart[n] = incl;
  if (lane < 2) tcnt[lane] = 0;
}

// fused: apply block offsets to rowstart + partition nodes by type
__global__ __launch_bounds__(256) void scan3_part_kernel(int* __restrict__ rowstart,
                                                         const int* __restrict__ boff,
                                                         const int* __restrict__ ntype,
                                                         int* __restrict__ idxbuf,
                                                         int* __restrict__ tcnt,
                                                         int n, int ncap) {
  int i = blockIdx.x * 256 + threadIdx.x;
  if (i < n) rowstart[i] += boff[i >> 10];
  int lane = threadIdx.x & 63;
  int t = (i < n) ? ntype[i] : -1;
  unsigned long long m0 = __ballot(t == 0);
  unsigned long long m1 = __ballot(t == 1);
  int b0 = 0, b1 = 0;
  if (lane == 0) {
    b0 = atomicAdd(&tcnt[0], (int)__popcll(m0));
    b1 = atomicAdd(&tcnt[1], (int)__popcll(m1));
  }
  b0 = __shfl(b0, 0);
  b1 = __shfl(b1, 0);
  unsigned long long below = (1ull << lane) - 1ull;
  if (t == 0) idxbuf[b0 + (int)__popcll(m0 & below)] = i;
  else if (t == 1) idxbuf[ncap + b1 + (int)__popcll(m1 & below)] = i;
}

// edata = byte offset src*768 + et*128, et duplicated in the low 2 bits.
__global__ __launch_bounds__(256) void fill_kernel(const int* __restrict__ src,
                                                   const int* __restrict__ dst,
                                                   const int* __restrict__ etype,
                                                   const int* __restrict__ rank,
                                                   const int* __restrict__ rowstart,
                                                   const int* __restrict__ deg8,
                                                   int* __restrict__ edata, int E) {
  int i = blockIdx.x * 256 + threadIdx.x;
  if (i < E) {
    int d = dst[i];
    int r = (i >> 8) & 7;
    int et = etype[i];
    int pos = rowstart[d] + deg8[d * 8 + r] + rank[i];
    edata[pos] = src[i] * 768 + et * 129;  // et*128 + et
  }
}

// ---------------- W fragment prep (both layers in one launch) ----------------

__device__ __forceinline__ void prep_w_body(const float* __restrict__ eW, int IN,
                                            int id, float* __restrict__ wfh,
                                            float* __restrict__ wfl) {
  int lane = id & 63;
  int fk = id >> 6;
  int KC = IN / 32;
  int kc = fk % KC, ct = fk / KC;
  int n = ct * 16 + (lane & 15);
  int kb = kc * 32 + ((lane >> 4) & 3) * 8;
  int half = (n >= 96) ? 1 : 0;
  int jj = n - 96 * half;
  int e = jj >> 5, o = jj & 31;
  const float* wp = eW + ((size_t)((e * 2 + half) * IN) + kb) * 32 + o;
  bf16x8_t hv, lv;
#pragma unroll
  for (int j = 0; j < 8; ++j) {
    unsigned short h, l;
    cvt_split(wp[(size_t)j * 32], h, l);
    hv[j] = (short)h;
    lv[j] = (short)l;
  }
  *(bf16x8_t*)(wfh + (size_t)id * 4) = hv;
  *(bf16x8_t*)(wfl + (size_t)id * 4) = lv;
}

__global__ __launch_bounds__(256) void prep_w_all(const float* __restrict__ eW0,
                                                  const float* __restrict__ eW1,
                                                  float* __restrict__ wf0h,
                                                  float* __restrict__ wf0l,
                                                  float* __restrict__ wf1h,
                                                  float* __restrict__ wf1l) {
  int b = blockIdx.x;
  int tx = threadIdx.x;
  if (b < 12) {
    prep_w_body(eW0, 128, b * 256 + tx, wf0h, wf0l);       // 12*4*64 = 3072 ids
  } else {
    int id = (b - 12) * 256 + tx;
    if (id < 1536) prep_w_body(eW1, 64, id, wf1h, wf1l);   // 12*2*64 = 1536 ids
  }
}

// ---------------- node projection GEMM via MFMA ----------------

template <int IN>
__global__ __launch_bounds__(256) void proj_mfma(const float* __restrict__ X,
                                                 const float* __restrict__ wfh,
                                                 const float* __restrict__ wfl,
                                                 float* __restrict__ P, int n) {
  constexpr int KC = IN / 32;
  __shared__ short Ah[4 * KC * 64 * 8];
  __shared__ short Al[4 * KC * 64 * 8];
  const int tx = threadIdx.x;
  const int base = blockIdx.x * 64;

  for (int q = tx; q < 4 * KC * 64; q += 256) {
    int lane = q & 63;
    int fk = q >> 6;
    int kc = fk % KC, nt = fk / KC;
    int node = base + nt * 16 + (lane & 15);
    int kb = kc * 32 + ((lane >> 4) & 3) * 8;
    float xs[8];
    if (node < n) {
      float4 a = *(const float4*)(X + (size_t)node * IN + kb);
      float4 b = *(const float4*)(X + (size_t)node * IN + kb + 4);
      xs[0] = a.x; xs[1] = a.y; xs[2] = a.z; xs[3] = a.w;
      xs[4] = b.x; xs[5] = b.y; xs[6] = b.z; xs[7] = b.w;
    } else {
#pragma unroll
      for (int j = 0; j < 8; ++j) xs[j] = 0.f;
    }
    bf16x8_t hv, lv;
#pragma unroll
    for (int j = 0; j < 8; ++j) {
      unsigned short h, l;
      cvt_split(xs[j], h, l);
      hv[j] = (short)h;
      lv[j] = (short)l;
    }
    *(bf16x8_t*)(Ah + (size_t)q * 8) = hv;
    *(bf16x8_t*)(Al + (size_t)q * 8) = lv;
  }
  __syncthreads();

  const int wave = tx >> 6;
  const int lane = tx & 63;

  f32x4_t acc[4][3];
#pragma unroll
  for (int nt = 0; nt < 4; ++nt)
#pragma unroll
    for (int c = 0; c < 3; ++c) acc[nt][c] = (f32x4_t){0.f, 0.f, 0.f, 0.f};

  for (int kc = 0; kc < KC; ++kc) {
    bf16x8_t Bh[3], Bl[3];
#pragma unroll
    for (int c = 0; c < 3; ++c) {
      int ct = wave * 3 + c;
      size_t idx = ((size_t)(ct * KC + kc) * 64 + lane) * 4;
      Bh[c] = *(const bf16x8_t*)(wfh + idx);
      Bl[c] = *(const bf16x8_t*)(wfl + idx);
    }
#pragma unroll
    for (int nt = 0; nt < 4; ++nt) {
      size_t idx = ((size_t)(nt * KC + kc) * 64 + lane) * 8;
      bf16x8_t ah = *(const bf16x8_t*)(Ah + idx);
      bf16x8_t al = *(const bf16x8_t*)(Al + idx);
#pragma unroll
      for (int c = 0; c < 3; ++c) {
        acc[nt][c] = __builtin_amdgcn_mfma_f32_16x16x32_bf16(ah, Bh[c], acc[nt][c], 0, 0, 0);
        acc[nt][c] = __builtin_amdgcn_mfma_f32_16x16x32_bf16(ah, Bl[c], acc[nt][c], 0, 0, 0);
        acc[nt][c] = __builtin_amdgcn_mfma_f32_16x16x32_bf16(al, Bh[c], acc[nt][c], 0, 0, 0);
      }
    }
  }

  const int row0 = ((lane >> 4) & 3) * 4;
  const int col = lane & 15;
#pragma unroll
  for (int nt = 0; nt < 4; ++nt) {
#pragma unroll
    for (int c = 0; c < 3; ++c) {
      int jcol = (wave * 3 + c) * 16 + col;
#pragma unroll
      for (int r = 0; r < 4; ++r) {
        int node = base + nt * 16 + row0 + r;
        if (node < n) P[(size_t)node * 192 + jcol] = acc[nt][c][r];
      }
    }
  }
}

// ---------------- edge aggregation (contiguous split per slot, unroll-8) ----------------

#define ACC_EDGE(pk, v)                                      \
  {                                                          \
    int et_ = (pk) & 3;                                      \
    float pb_ = (et_ == 0) ? pdb0 : ((et_ == 1) ? pdb1 : pdb2); \
    float m_ = fmaxf((v) + pb_, 0.f);                        \
    a0 += (et_ == 0) ? m_ : 0.f;                             \
    a1 += (et_ == 1) ? m_ : 0.f;                             \
    a2 += (et_ == 2) ? m_ : 0.f;                             \
    c0 += (et_ == 0);                                        \
    c1 += (et_ == 1);                                        \
  }

__global__ __launch_bounds__(256) void aggregate_kernel(const float* __restrict__ P,
                                                        const int* __restrict__ rowstart,
                                                        const int* __restrict__ edata,
                                                        const float* __restrict__ eb,
                                                        float* __restrict__ h, int n) {
  int wid = (blockIdx.x * 256 + threadIdx.x) >> 6;
  if (wid >= n) return;
  int lane = threadIdx.x & 63;
  int o = lane & 31, slot = lane >> 5;
  const float* Pd = P + (size_t)wid * 192 + 96;
  float pdb0 = Pd[o] + eb[o];
  float pdb1 = Pd[32 + o] + eb[32 + o];
  float pdb2 = Pd[64 + o] + eb[64 + o];
  int s = rowstart[wid], e = rowstart[wid + 1];
  int len = e - s;
  int half1 = (len + 1) >> 1;
  int beg = slot ? s + half1 : s;       // contiguous chunk per slot
  int end = slot ? e : s + half1;
  const char* Pb = (const char*)P;
  int o4 = o * 4;
  float a0 = 0.f, a1 = 0.f, a2 = 0.f;
  int c0 = 0, c1 = 0;
  int i = beg;
  // 8 edges per slot-iteration -> 16 independent P loads in flight per wave
  for (; i + 7 < end; i += 8) {
    int pk[8];
#pragma unroll
    for (int u = 0; u < 8; ++u) pk[u] = edata[i + u];
    float v[8];
#pragma unroll
    for (int u = 0; u < 8; ++u) v[u] = *(const float*)(Pb + (pk[u] & ~3) + o4);
#pragma unroll
    for (int u = 0; u < 8; ++u) ACC_EDGE(pk[u], v[u])
  }
  for (; i < end; ++i) {
    int pk = edata[i];
    float v = *(const float*)(Pb + (pk & ~3) + o4);
    ACC_EDGE(pk, v)
  }
  a0 += __shfl_xor(a0, 32);
  a1 += __shfl_xor(a1, 32);
  a2 += __shfl_xor(a2, 32);
  c0 += __shfl_xor(c0, 32);
  c1 += __shfl_xor(c1, 32);
  if (slot == 0) {
    float* hn = h + (size_t)wid * 96;
    hn[o] = a0 / fmaxf((float)c0, 1.f);
    hn[32 + o] = a1 / fmaxf((float)c1, 1.f);
    hn[64 + o] = a2 / fmaxf((float)(len - c0 - c1), 1.f);
  }
}

// ---------------- node MLP (type-partitioned), quad-transposed Ws ----------------

template <int OUT>
__global__ __launch_bounds__(256) void mlp2_kernel(const float* __restrict__ H,
                                                   const float* __restrict__ nW,
                                                   const float* __restrict__ nb,
                                                   const int* __restrict__ idxbuf,
                                                   const int* __restrict__ tcnt,
                                                   float* __restrict__ out, int ncap) {
  constexpr int CO = OUT / 32;
  __shared__ float Xs[64 * 32];
  __shared__ float Ws[8 * OUT * 4];

  int c0 = tcnt[0];
  int nb0 = (c0 + 63) >> 6;
  int t, base, cnt;
  if ((int)blockIdx.x < nb0) {
    t = 0; base = blockIdx.x << 6; cnt = c0;
  } else {
    t = 1; base = ((int)blockIdx.x - nb0) << 6; cnt = tcnt[1];
    if (base >= cnt) return;
  }
  const float* W = nW + (size_t)t * 96 * OUT;
  const float* bias = nb + t * OUT;
  const int* il = idxbuf + (size_t)t * ncap;

  const int tx = threadIdx.x;
  const int t32 = tx & 31;
  const int ng = tx >> 5;

  float acc[8][CO];
#pragma unroll
  for (int i = 0; i < 8; ++i)
#pragma unroll
    for (int c = 0; c < CO; ++c) acc[i][c] = 0.f;

  for (int k0 = 0; k0 < 96; k0 += 32) {
    for (int id = tx; id < 512; id += 256) {
      int i = id >> 3, kk4 = (id & 7) * 4;
      float4 v = make_float4(0.f, 0.f, 0.f, 0.f);
      if (base + i < cnt) {
        int row = il[base + i];
        v = *(const float4*)(H + (size_t)row * 96 + k0 + kk4);
      }
      *(float4*)(Xs + i * 32 + kk4) = v;
    }
    for (int id = tx; id < 8 * OUT; id += 256) {
      int g = id / OUT;
      int j = id % OUT;
      const float* wp = W + (size_t)(k0 + 4 * g) * OUT + j;
      float4 v = make_float4(wp[0], wp[OUT], wp[2 * OUT], wp[3 * OUT]);
      *(float4*)(Ws + (size_t)id * 4) = v;
    }
    __syncthreads();
#pragma unroll
    for (int g = 0; g < 8; ++g) {
      float4 xv[8], wv[CO];
#pragma unroll
      for (int i = 0; i < 8; ++i) xv[i] = *(const float4*)(Xs + (ng * 8 + i) * 32 + 4 * g);
#pragma unroll
      for (int c = 0; c < CO; ++c) wv[c] = *(const float4*)(Ws + ((size_t)g * OUT + t32 + 32 * c) * 4);
#pragma unroll
      for (int i = 0; i < 8; ++i)
#pragma unroll
        for (int c = 0; c < CO; ++c) {
          acc[i][c] = fmaf(xv[i].x, wv[c].x, acc[i][c]);
          acc[i][c] = fmaf(xv[i].y, wv[c].y, acc[i][c]);
          acc[i][c] = fmaf(xv[i].z, wv[c].z, acc[i][c]);
          acc[i][c] = fmaf(xv[i].w, wv[c].w, acc[i][c]);
        }
    }
    __syncthreads();
  }

  float bj[CO];
#pragma unroll
  for (int c = 0; c < CO; ++c) bj[c] = bias[t32 + 32 * c];
#pragma unroll
  for (int i = 0; i < 8; ++i) {
    int slot = base + ng * 8 + i;
    if (slot < cnt) {
      int row = il[slot];
#pragma unroll
      for (int c = 0; c < CO; ++c)
        out[(size_t)row * OUT + t32 + 32 * c] = fmaxf(acc[i][c] + bj[c], 0.f);
    }
  }
}

// ---------------- launch ----------------

extern "C" void kernel_launch(void* const* d_in, const int* in_sizes, int n_in,
                              void* d_out, int out_size, void* d_ws, size_t ws_size,
                              hipStream_t stream) {
  const float* nf    = (const float*)d_in[0];
  const int*   eidx  = (const int*)d_in[1];
  const int*   etype = (const int*)d_in[2];
  const int*   ntype = (const int*)d_in[3];
  const float* eW0   = (const float*)d_in[4];
  const float* eb0   = (const float*)d_in[5];
  const float* nW0   = (const float*)d_in[6];
  const float* nb0   = (const float*)d_in[7];
  const float* eW1   = (const float*)d_in[8];
  const float* eb1   = (const float*)d_in[9];
  const float* nW1   = (const float*)d_in[10];
  const float* nb1   = (const float*)d_in[11];
  const int N = in_sizes[3];
  const int E = in_sizes[2];
  const int* srcv = eidx;
  const int* dstv = eidx + E;

  // workspace layout; rank aliases h96, deg8 aliases h64 (CSR build completes
  // before aggregate/mlp write those buffers — stream-ordered).
  float* P   = (float*)d_ws;                     // N*192
  float* h96 = P + (size_t)N * 192;              // N*96
  float* h64 = h96 + (size_t)N * 96;             // N*64
  int* rowstart = (int*)(h64 + (size_t)N * 64);  // N+1 (padded)
  int* tcnt     = rowstart + ((N + 4) & ~3);     // 2
  int* bsum     = tcnt + 2;                      // 64
  int* boff     = bsum + 64;                     // 64
  int* idxbuf   = boff + 64;                     // 2*N
  int* edata    = idxbuf + 2 * N;                // E
  float* wf0h   = (float*)(edata + E);           // 12288
  float* wf0l   = wf0h + 12288;                  // 12288
  float* wf1h   = wf0l + 12288;                  // 6144
  float* wf1l   = wf1h + 6144;                   // 6144
  int* rank     = (int*)h96;                     // E  (alias)
  int* deg8     = (int*)h64;                     // 8N (alias)

  const int nsb = (N + 1023) / 1024;
  const int egrid = (E + 255) / 256;

  hipMemsetAsync(deg8, 0, (size_t)N * 8 * sizeof(int), stream);
  prep_w_all<<<18, 256, 0, stream>>>(eW0, eW1, wf0h, wf0l, wf1h, wf1l);
  rank_kernel<<<egrid, 256, 0, stream>>>(dstv, deg8, rank, E);
  scan1_kernel<<<nsb, 256, 0, stream>>>(deg8, rowstart, bsum, N);
  scan2_kernel<<<1, 64, 0, stream>>>(bsum, boff, nsb, rowstart, N, tcnt);
  scan3_part_kernel<<<(N + 255) / 256, 256, 0, stream>>>(rowstart, boff, ntype, idxbuf, tcnt, N, N);
  fill_kernel<<<egrid, 256, 0, stream>>>(srcv, dstv, etype, rank, rowstart, deg8, edata, E);

  const int pgrid = (N + 63) / 64;
  int agrid = (N + 3) / 4;
  int mgrid = (N + 63) / 64 + 2;

  // layer 0: 128 -> 64
  proj_mfma<128><<<pgrid, 256, 0, stream>>>(nf, wf0h, wf0l, P, N);
  aggregate_kernel<<<agrid, 256, 0, stream>>>(P, rowstart, edata, eb0, h96, N);
  mlp2_kernel<64><<<mgrid, 256, 0, stream>>>(h96, nW0, nb0, idxbuf, tcnt, h64, N);

  // layer 1: 64 -> 128
  proj_mfma<64><<<pgrid, 256, 0, stream>>>(h64, wf1h, wf1l, P, N);
  aggregate_kernel<<<agrid, 256, 0, stream>>>(P, rowstart, edata, eb1, h96, N);
  mlp2_kernel<128><<<mgrid, 256, 0, stream>>>(h96, nW1, nb1, idxbuf, tcnt, (float*)d_out, N);
}